// Round 5
// baseline (5258.999 us; speedup 1.0000x reference)
//
#include <hip/hip_runtime.h>
#include <hip/hip_bf16.h>
#include <hip/hip_cooperative_groups.h>

namespace cg = cooperative_groups;

// ---------------------------------------------------------------------------
// Shapes: B=64, P=196, ENC=2048, E=H=A=512, V=10000, L=21 -> T=20
// All GEMMs on MFMA via split-bf16 (hi+lo): C = Ah@Bh + Ah@Bl + Al@Bh.
// Packed fragment layout (16-row tile x 32-k chunk -> 64 lanes x 8 bf16):
//   flat = (((mn>>4)*KC + (k>>5))*64 + ((k&31)>>3)*16 + (mn&15))*8 + (k&7)
// 20-step recurrence: ONE cooperative kernel, 256 blocks (= 1 block/CU ->
// co-residency guaranteed at any VGPR count), grid.sync() between phases.
// Fallback to per-phase kernel launches if the coop launch is rejected.
// ---------------------------------------------------------------------------

#define TB 256

typedef __bf16 bf16x8 __attribute__((ext_vector_type(8)));
typedef float f32x4 __attribute__((ext_vector_type(4)));
typedef unsigned short u16x8 __attribute__((ext_vector_type(8)));
typedef unsigned short u16x4 __attribute__((ext_vector_type(4)));
typedef unsigned short ushort_t;

__device__ __forceinline__ ushort_t f2bf(float x) {
    unsigned u = __builtin_bit_cast(unsigned, x);
    u += 0x7fffu + ((u >> 16) & 1u);          // round-to-nearest-even
    return (ushort_t)(u >> 16);
}
__device__ __forceinline__ float bf2f(ushort_t b) {
    return __builtin_bit_cast(float, (unsigned)b << 16);
}
__device__ __forceinline__ void store_pack(
    ushort_t* __restrict__ Ph, ushort_t* __restrict__ Pl,
    int KC, int m, int k, float v)
{
    const size_t flat = ((((size_t)(m >> 4) * KC + (k >> 5)) * 64)
                         + ((k & 31) >> 3) * 16 + (m & 15)) * 8 + (k & 7);
    const ushort_t h = f2bf(v);
    Ph[flat] = h;
    Pl[flat] = f2bf(v - bf2f(h));
}

// ------------------------- weight pack kernel ------------------------------
__global__ __launch_bounds__(TB) void pack_b(
    const float* __restrict__ W, int Nsrc, int ntCount, int KC,
    ushort_t* __restrict__ Bh, ushort_t* __restrict__ Bl, int ntBase)
{
    const int g = blockIdx.x * TB + threadIdx.x;
    const int lane = g & 63;
    const int kc = (g >> 6) % KC;
    const int nt = g / (64 * KC);
    if (nt >= ntCount) return;
    const int n = nt * 16 + (lane & 15);
    const int kb = kc * 32 + (lane >> 4) * 8;
    u16x8 hv, lv;
    #pragma unroll
    for (int e = 0; e < 8; ++e) {
        const float x = (n < Nsrc) ? W[(size_t)(kb + e) * Nsrc + n] : 0.f;
        const ushort_t h = f2bf(x);
        hv[e] = h;
        lv[e] = f2bf(x - bf2f(h));
    }
    const size_t flat = (((size_t)(ntBase + nt) * KC + kc) * 64 + lane) * 8;
    *(u16x8*)&Bh[flat] = hv;
    *(u16x8*)&Bl[flat] = lv;
}

// ------------------------- MFMA tile compute -------------------------------
template<int MT, int NT, int WR, int WC>
__device__ __forceinline__ void mfma_tile(
    const ushort_t* lds, int wr, int wc, int lane,
    f32x4 acc[MT / WR][NT / WC])
{
    constexpr int MFR = MT / WR, NFR = NT / WC;
    bf16x8 ah[MFR], al[MFR];
    #pragma unroll
    for (int i = 0; i < MFR; ++i) {
        ah[i] = __builtin_bit_cast(bf16x8, *(const u16x8*)&lds[(wr * MFR + i) * 512 + lane * 8]);
        al[i] = __builtin_bit_cast(bf16x8, *(const u16x8*)&lds[(MT + wr * MFR + i) * 512 + lane * 8]);
    }
    #pragma unroll
    for (int j = 0; j < NFR; ++j) {
        const bf16x8 bh = __builtin_bit_cast(bf16x8, *(const u16x8*)&lds[(2 * MT + wc * NFR + j) * 512 + lane * 8]);
        const bf16x8 bl = __builtin_bit_cast(bf16x8, *(const u16x8*)&lds[(2 * MT + NT + wc * NFR + j) * 512 + lane * 8]);
        #pragma unroll
        for (int i = 0; i < MFR; ++i) {
            acc[i][j] = __builtin_amdgcn_mfma_f32_16x16x32_bf16(ah[i], bh, acc[i][j], 0, 0, 0);
            acc[i][j] = __builtin_amdgcn_mfma_f32_16x16x32_bf16(ah[i], bl, acc[i][j], 0, 0, 0);
            acc[i][j] = __builtin_amdgcn_mfma_f32_16x16x32_bf16(al[i], bh, acc[i][j], 0, 0, 0);
        }
    }
}

// ------------- device-side packed GEMM (partial, no bias) ------------------
template<int MT, int NT, int WR, int WC>
__device__ __forceinline__ void dev_gemm_partial(
    ushort_t* lds,
    const ushort_t* __restrict__ Ah, const ushort_t* __restrict__ Al,
    const ushort_t* __restrict__ Bh, const ushort_t* __restrict__ Bl,
    int KC, int kc0, int kcN, int mb, int nb,
    float* __restrict__ Cout, int ldc)
{
    constexpr int MFR = MT / WR, NFR = NT / WC, CH = 2 * (MT + NT);
    const int tid = threadIdx.x, wid = tid >> 6, lane = tid & 63;
    const int wr = wid / WC, wc = wid % WC;

    f32x4 acc[MFR][NFR];
    #pragma unroll
    for (int i = 0; i < MFR; ++i)
        #pragma unroll
        for (int j = 0; j < NFR; ++j)
            acc[i][j] = f32x4{0.f, 0.f, 0.f, 0.f};

    for (int kc = kc0; kc < kc0 + kcN; ++kc) {
        __syncthreads();
        #pragma unroll
        for (int cc = 0; cc < CH / 4; ++cc) {
            const int c = cc * 4 + wid;
            const ushort_t* src;
            if (c < MT)                src = Ah + ((size_t)(mb * MT + c) * KC + kc) * 512;
            else if (c < 2 * MT)       src = Al + ((size_t)(mb * MT + c - MT) * KC + kc) * 512;
            else if (c < 2 * MT + NT)  src = Bh + ((size_t)(nb * NT + c - 2 * MT) * KC + kc) * 512;
            else                       src = Bl + ((size_t)(nb * NT + c - 2 * MT - NT) * KC + kc) * 512;
            *(u16x8*)&lds[c * 512 + lane * 8] = *(const u16x8*)(src + lane * 8);
        }
        __syncthreads();
        mfma_tile<MT, NT, WR, WC>(lds, wr, wc, lane, acc);
    }

    #pragma unroll
    for (int i = 0; i < MFR; ++i)
        #pragma unroll
        for (int j = 0; j < NFR; ++j) {
            const int col = nb * NT * 16 + (wc * NFR + j) * 16 + (lane & 15);
            const int rbase = mb * MT * 16 + (wr * MFR + i) * 16 + ((lane >> 4) << 2);
            #pragma unroll
            for (int r = 0; r < 4; ++r)
                Cout[(size_t)(rbase + r) * ldc + col] = acc[i][j][r];
        }
}

// ------------------------- generic packed MFMA GEMM (standalone) -----------
template<int MT, int NT, int WR, int WC>
__global__ __launch_bounds__(TB) void gemm_mfma(
    const ushort_t* __restrict__ Ah, const ushort_t* __restrict__ Al,
    const ushort_t* __restrict__ Bh, const ushort_t* __restrict__ Bl,
    int KC, int kcPer,
    const float* __restrict__ bias,
    float* __restrict__ C, int ldc, int Ncols, size_t cPartStride)
{
    constexpr int MFR = MT / WR, NFR = NT / WC, CH = 2 * (MT + NT);
    __shared__ __align__(16) ushort_t lds[CH * 512];
    const int tid = threadIdx.x, wid = tid >> 6, lane = tid & 63;
    const int wr = wid / WC, wc = wid % WC;

    const int tot = gridDim.x * gridDim.y;
    const int lin = blockIdx.x + gridDim.x * blockIdx.y;
    const int q = tot >> 3, r = tot & 7;
    const int xcd = lin & 7, jj = lin >> 3;
    const int base = (xcd < r) ? xcd * (q + 1) : r * (q + 1) + (xcd - r) * q;
    const int lin2 = base + jj;
    const int nb = lin2 / gridDim.y;
    const int mb = lin2 % gridDim.y;

    const int kc0 = blockIdx.z * kcPer;

    f32x4 acc[MFR][NFR];
    #pragma unroll
    for (int i = 0; i < MFR; ++i)
        #pragma unroll
        for (int j = 0; j < NFR; ++j)
            acc[i][j] = f32x4{0.f, 0.f, 0.f, 0.f};

    for (int kc = kc0; kc < kc0 + kcPer; ++kc) {
        __syncthreads();
        #pragma unroll
        for (int cc = 0; cc < CH / 4; ++cc) {
            const int c = cc * 4 + wid;
            const ushort_t* src;
            if (c < MT)                src = Ah + ((size_t)(mb * MT + c) * KC + kc) * 512;
            else if (c < 2 * MT)       src = Al + ((size_t)(mb * MT + c - MT) * KC + kc) * 512;
            else if (c < 2 * MT + NT)  src = Bh + ((size_t)(nb * NT + c - 2 * MT) * KC + kc) * 512;
            else                       src = Bl + ((size_t)(nb * NT + c - 2 * MT - NT) * KC + kc) * 512;
            *(u16x8*)&lds[c * 512 + lane * 8] = *(const u16x8*)(src + lane * 8);
        }
        __syncthreads();
        mfma_tile<MT, NT, WR, WC>(lds, wr, wc, lane, acc);
    }

    C += (size_t)blockIdx.z * cPartStride;
    #pragma unroll
    for (int i = 0; i < MFR; ++i)
        #pragma unroll
        for (int j = 0; j < NFR; ++j) {
            const int col = nb * NT * 16 + (wc * NFR + j) * 16 + (lane & 15);
            if (col < Ncols) {
                const float bv = bias ? bias[col] : 0.f;
                const int rbase = mb * MT * 16 + (wr * MFR + i) * 16 + ((lane >> 4) << 2);
                #pragma unroll
                for (int r = 0; r < 4; ++r)
                    C[(size_t)(rbase + r) * ldc + col] = acc[i][j][r] + bv;
            }
        }
}

// ------------------------- att1 GEMM (A = fp32 features, on-the-fly split) -
__global__ __launch_bounds__(TB) void gemm_att1(
    const float* __restrict__ A,
    const ushort_t* __restrict__ Bh, const ushort_t* __restrict__ Bl,
    const float* __restrict__ bias, float* __restrict__ C)
{
    __shared__ __align__(16) ushort_t lds[32 * 512];
    const int tid = threadIdx.x, wid = tid >> 6, lane = tid & 63;
    const int wr = wid >> 1, wc = wid & 1;

    const int lin = blockIdx.x + (blockIdx.y << 2);   // 392 blocks = 8 * 49
    const int lin2 = (lin & 7) * 49 + (lin >> 3);
    const int nb = lin2 & 3, mb = lin2 >> 2;

    f32x4 acc[4][4];
    #pragma unroll
    for (int i = 0; i < 4; ++i)
        #pragma unroll
        for (int j = 0; j < 4; ++j)
            acc[i][j] = f32x4{0.f, 0.f, 0.f, 0.f};

    for (int kc = 0; kc < 64; ++kc) {
        __syncthreads();
        #pragma unroll
        for (int cc = 0; cc < 4; ++cc) {
            const int c = cc * 4 + wid;
            const ushort_t* src = (c < 8)
                ? Bh + ((size_t)(nb * 8 + c) * 64 + kc) * 512
                : Bl + ((size_t)(nb * 8 + c - 8) * 64 + kc) * 512;
            *(u16x8*)&lds[(16 + c) * 512 + lane * 8] = *(const u16x8*)(src + lane * 8);
        }
        #pragma unroll
        for (int p = 0; p < 4; ++p) {
            const int id = p * 256 + tid;
            const int row = id >> 3, c4 = id & 7;
            const float4 a = *(const float4*)&A[(size_t)(mb * 128 + row) * 2048 + kc * 32 + c4 * 4];
            const float xv[4] = {a.x, a.y, a.z, a.w};
            u16x4 hv, lv;
            #pragma unroll
            for (int qq = 0; qq < 4; ++qq) {
                const ushort_t h = f2bf(xv[qq]);
                hv[qq] = h;
                lv[qq] = f2bf(xv[qq] - bf2f(h));
            }
            const int base = ((c4 >> 1) * 16 + (row & 15)) * 8 + (c4 & 1) * 4;
            const int chunk = row >> 4;
            *(u16x4*)&lds[chunk * 512 + base] = hv;
            *(u16x4*)&lds[(8 + chunk) * 512 + base] = lv;
        }
        __syncthreads();
        mfma_tile<8, 8, 2, 2>(lds, wr, wc, lane, acc);
    }

    #pragma unroll
    for (int i = 0; i < 4; ++i)
        #pragma unroll
        for (int j = 0; j < 4; ++j) {
            const int col = nb * 128 + (wc * 4 + j) * 16 + (lane & 15);
            const float bv = bias[col];
            const int rbase = mb * 128 + (wr * 4 + i) * 16 + ((lane >> 4) << 2);
            #pragma unroll
            for (int r = 0; r < 4; ++r)
                C[(size_t)(rbase + r) * 512 + col] = acc[i][j][r] + bv;
        }
}

// ------------------------- fp32 GEMM (one-time h0/c0 only) -----------------
__device__ __forceinline__ void gemm_body(
    float (*As)[68], float (*Ws)[68],
    const float* __restrict__ A, int lda,
    const float* __restrict__ W, int ldw,
    float* __restrict__ C, int ldc,
    int nTile, int N, int K)
{
    const int tid = threadIdx.x;
    const int tn = tid & 15;
    const int tm = tid >> 4;
    const int n0 = nTile * 64;

    float acc[4][4] = {{0.f}};

    for (int k0 = 0; k0 < K; k0 += 32) {
        {
            int r  = tid >> 3;
            int cc = (tid & 7) * 4;
            #pragma unroll
            for (int rr = 0; rr < 64; rr += 32) {
                const float4 a = *(const float4*)&A[(size_t)(rr + r) * lda + (k0 + cc)];
                As[cc + 0][rr + r] = a.x;
                As[cc + 1][rr + r] = a.y;
                As[cc + 2][rr + r] = a.z;
                As[cc + 3][rr + r] = a.w;
            }
        }
        {
            int r  = tid >> 4;
            int cc = (tid & 15) * 4;
            #pragma unroll
            for (int rr = 0; rr < 32; rr += 16) {
                const float4 w = *(const float4*)&W[(size_t)(k0 + rr + r) * ldw + (n0 + cc)];
                *(float4*)&Ws[rr + r][cc] = w;
            }
        }
        __syncthreads();
        #pragma unroll
        for (int kk = 0; kk < 32; ++kk) {
            const float4 a = *(const float4*)&As[kk][tm * 4];
            const float4 w = *(const float4*)&Ws[kk][tn * 4];
            const float av[4] = {a.x, a.y, a.z, a.w};
            const float wv[4] = {w.x, w.y, w.z, w.w};
            #pragma unroll
            for (int i = 0; i < 4; ++i)
                #pragma unroll
                for (int j = 0; j < 4; ++j)
                    acc[i][j] = fmaf(av[i], wv[j], acc[i][j]);
        }
        __syncthreads();
    }

    #pragma unroll
    for (int i = 0; i < 4; ++i) {
        const int m = tm * 4 + i;
        #pragma unroll
        for (int j = 0; j < 4; ++j)
            C[(size_t)m * ldc + (n0 + tn * 4 + j)] = acc[i][j];
    }
}

__global__ __launch_bounds__(TB) void gemm_part(
    const float* __restrict__ A, int lda,
    const float* __restrict__ W, int ldw,
    float* __restrict__ Cpart, int ldc, int N, int Kchunk)
{
    __shared__ float As[32][68];
    __shared__ float Ws[32][68];
    const int ks = blockIdx.y;
    gemm_body(As, Ws,
              A + (size_t)ks * Kchunk, lda,
              W + (size_t)ks * Kchunk * ldw, ldw,
              Cpart + (size_t)ks * 64 * ldc, ldc,
              blockIdx.x, N, Kchunk);
}

// ------------------------- loop phases (shared by coop + fallback) ---------
struct LoopArgs {
    const ushort_t *WdfhH, *WdfhL;   // [Wd|Wf|Wh] packed (288 nt, KC=16)
    const ushort_t *Wih2H, *Wih2L;   // W_ih[512:]  packed (128 nt, KC=64)
    const float *att1;               // (64,196,512)
    const float *bd, *Wfull, *bf, *b_hh;
    const float *eW;                 // (64,20,2048), includes b_ih
    const float *features;           // (64,196,2048)
    float *hga;                      // (4,64,4608) partials
    float *gatesp;                   // (8,64,2048) partials
    float *scores;                   // (64,196)
    float *c;                        // (64,512)
    ushort_t *hPh, *hPl;             // packed h    (M64,  K512,  KC=16)
    ushort_t *gPh, *gPl;             // packed gated(M64,  K2048, KC=64)
    ushort_t *sPh, *sPl;             // packed hseq (M1280,K512,  KC=16)
};

// P1: hga[ks] = h @ [Wd|Wf|Wh] partials. 144 blocks = 36 nt x 4 ks.
__device__ __forceinline__ void phase1(ushort_t* smem, const LoopArgs& A, int blk)
{
    const int nb = blk % 36, ks = blk / 36;
    dev_gemm_partial<4, 8, 2, 2>(smem, A.hPh, A.hPl, A.WdfhH, A.WdfhL,
        16, ks * 4, 4, 0, nb,
        A.hga + (size_t)ks * 64 * 4608, 4608);
}

// P2: scores. 256 blocks = 64 b x 4 pg (49 p's each).
__device__ __forceinline__ void phase2(float* smf, const LoopArgs& A, int blk)
{
    const int b = blk >> 2, pg = blk & 3;
    const int tid = threadIdx.x, wave = tid >> 6, lane = tid & 63;
    float* a2 = smf;
    float* wf = smf + 512;
    for (int i = tid; i < 512; i += TB) {
        float v = A.bd[i];
        #pragma unroll
        for (int s = 0; s < 4; ++s)
            v += A.hga[(size_t)s * 64 * 4608 + (size_t)b * 4608 + i];
        a2[i] = v;
        wf[i] = A.Wfull[i];
    }
    __syncthreads();
    for (int pl = wave; pl < 49; pl += 4) {
        const int p = pg * 49 + pl;
        const float* row = A.att1 + ((size_t)b * 196 + p) * 512;
        float s = 0.f;
        #pragma unroll
        for (int k = lane; k < 512; k += 64) {
            const float v = row[k] + a2[k];
            s = fmaf(fmaxf(v, 0.f), wf[k], s);
        }
        #pragma unroll
        for (int o = 32; o; o >>= 1) s += __shfl_xor(s, o);
        if (lane == 0) A.scores[b * 196 + p] = s;
    }
    __syncthreads();
}

// P3: softmax + awe + gate + pack gated. 256 blocks = 64 b x 4; 2 e's/thread.
__device__ __forceinline__ void phase3(float* smf, const LoopArgs& A, int blk)
{
    const int b = blk >> 2, e4 = blk & 3;
    const int tid = threadIdx.x, wave = tid >> 6, lane = tid & 63;
    float* al   = smf;          // [196]
    float* redm = smf + 200;    // [4]
    float* reds = smf + 204;    // [4]

    const float sv = (tid < 196) ? A.scores[b * 196 + tid] : -1e30f;
    float m = sv;
    #pragma unroll
    for (int o = 32; o; o >>= 1) m = fmaxf(m, __shfl_xor(m, o));
    if (lane == 0) redm[wave] = m;
    __syncthreads();
    m = fmaxf(fmaxf(redm[0], redm[1]), fmaxf(redm[2], redm[3]));

    const float e = (tid < 196) ? expf(sv - m) : 0.f;
    float s = e;
    #pragma unroll
    for (int o = 32; o; o >>= 1) s += __shfl_xor(s, o);
    if (lane == 0) reds[wave] = s;
    __syncthreads();
    s = reds[0] + reds[1] + reds[2] + reds[3];

    if (tid < 196) al[tid] = e / s;
    __syncthreads();

    const int eg0 = e4 * TB + tid;          // 0..1023 ; second elem +1024
    const float* f = A.features + (size_t)b * 196 * 2048 + eg0;
    float acc0 = 0.f, acc1 = 0.f;
    #pragma unroll 4
    for (int p = 0; p < 196; ++p) {
        const float w = al[p];
        acc0 = fmaf(w, f[(size_t)p * 2048], acc0);
        acc1 = fmaf(w, f[(size_t)p * 2048 + 1024], acc1);
    }

    float gp0 = A.bf[eg0], gp1 = A.bf[eg0 + 1024];
    #pragma unroll
    for (int ss = 0; ss < 4; ++ss) {
        const float* hp = A.hga + (size_t)ss * 64 * 4608 + (size_t)b * 4608 + 512;
        gp0 += hp[eg0];
        gp1 += hp[eg0 + 1024];
    }
    const float g0 = 1.f / (1.f + expf(-gp0));
    const float g1 = 1.f / (1.f + expf(-gp1));
    store_pack(A.gPh, A.gPl, 64, b, eg0, g0 * acc0);
    store_pack(A.gPh, A.gPl, 64, b, eg0 + 1024, g1 * acc1);
    __syncthreads();
}

// P4: gatesp[ks] = gated @ W_ih[512:] partials. 256 blocks = 32 nt x 8 ks.
__device__ __forceinline__ void phase4(ushort_t* smem, const LoopArgs& A, int blk)
{
    const int nb = blk & 31, ks = blk >> 5;
    dev_gemm_partial<4, 4, 2, 2>(smem, A.gPh, A.gPl, A.Wih2H, A.Wih2L,
        64, ks * 8, 8, 0, nb,
        A.gatesp + (size_t)ks * 64 * 2048, 2048);
}

// P5: lstm pointwise + pack h/hseq. 128 blocks.
__device__ __forceinline__ void phase5(const LoopArgs& A, int blk, int t)
{
    const int idx = blk * TB + threadIdx.x;     // 0..32767
    const int b = idx >> 9, j = idx & 511;
    float g[4];
    #pragma unroll
    for (int comp = 0; comp < 4; ++comp) {
        const int col = comp * 512 + j;
        float v = A.b_hh[col] + A.eW[((size_t)b * 20 + t) * 2048 + col];
        #pragma unroll
        for (int s = 0; s < 8; ++s)
            v += A.gatesp[(size_t)s * 64 * 2048 + (size_t)b * 2048 + col];
        #pragma unroll
        for (int s = 0; s < 4; ++s)
            v += A.hga[(size_t)s * 64 * 4608 + (size_t)b * 4608 + 2560 + col];
        g[comp] = v;
    }
    const float si = 1.f / (1.f + expf(-g[0]));
    const float sf = 1.f / (1.f + expf(-g[1]));
    const float gg = tanhf(g[2]);
    const float so = 1.f / (1.f + expf(-g[3]));
    const float cn = sf * A.c[idx] + si * gg;
    A.c[idx] = cn;
    const float hn = so * tanhf(cn);
    store_pack(A.hPh, A.hPl, 16, b, j, hn);
    store_pack(A.sPh, A.sPl, 16, b * 20 + t, j, hn);
}

// ------------------------- cooperative mega-kernel (256 blocks) ------------
__global__ __launch_bounds__(TB, 2) void loop_mega(LoopArgs A)
{
    cg::grid_group gridg = cg::this_grid();
    __shared__ __align__(16) ushort_t smem[24 * 512];   // 24 KB
    float* smf = (float*)smem;
    const int blk = blockIdx.x;

    for (int t = 0; t < 20; ++t) {
        if (blk < 144) phase1(smem, A, blk);
        gridg.sync();
        phase2(smf, A, blk);
        gridg.sync();
        phase3(smf, A, blk);
        gridg.sync();
        phase4(smem, A, blk);
        gridg.sync();
        if (blk < 128) phase5(A, blk, t);
        gridg.sync();
    }
}

// ------------------------- fallback per-phase kernels -----------------------
__global__ __launch_bounds__(TB) void p1_k(LoopArgs A) {
    __shared__ __align__(16) ushort_t smem[24 * 512];
    phase1(smem, A, blockIdx.x);
}
__global__ __launch_bounds__(TB) void p2_k(LoopArgs A) {
    __shared__ __align__(16) float smf[1024];
    phase2(smf, A, blockIdx.x);
}
__global__ __launch_bounds__(TB) void p3_k(LoopArgs A) {
    __shared__ __align__(16) float smf[256];
    phase3(smf, A, blockIdx.x);
}
__global__ __launch_bounds__(TB) void p4_k(LoopArgs A) {
    __shared__ __align__(16) ushort_t smem[16 * 512];
    phase4(smem, A, blockIdx.x);
}
__global__ __launch_bounds__(TB) void p5_k(LoopArgs A, int t) {
    phase5(A, blockIdx.x, t);
}

// ------------------------- precompute helpers ------------------------------
__global__ __launch_bounds__(TB) void mean_feat(
    const float* __restrict__ features, float* __restrict__ mean_enc)
{
    const int b = blockIdx.y;
    const int e = blockIdx.x * TB + threadIdx.x;
    const float* f = features + (size_t)b * 196 * 2048 + e;
    float s = 0.f;
    #pragma unroll 4
    for (int p = 0; p < 196; ++p) s += f[(size_t)p * 2048];
    mean_enc[b * 2048 + e] = s * (1.f / 196.f);
}

__global__ __launch_bounds__(TB) void gather_emb_pack(
    const int* __restrict__ captions,
    const float* __restrict__ emb,
    ushort_t* __restrict__ Ph, ushort_t* __restrict__ Pl)
{
    const int bt = blockIdx.x;          // 0..1279
    const int b = bt / 20;
    const int t = bt % 20;
    const int tok = captions[b * 21 + t];
    for (int e = threadIdx.x; e < 512; e += TB)
        store_pack(Ph, Pl, 16, bt, e, emb[(size_t)tok * 512 + e]);
}

__global__ __launch_bounds__(TB) void reduce_hc(
    const float* __restrict__ h0p, const float* __restrict__ c0p,
    const float* __restrict__ bh0, const float* __restrict__ bc0,
    ushort_t* __restrict__ hPh, ushort_t* __restrict__ hPl,
    float* __restrict__ c)
{
    const int idx = blockIdx.x * TB + threadIdx.x;   // 0..65535
    const int half = idx >> 15;
    const int i = idx & 32767;
    const int j = i & 511;
    const float* P = half ? c0p : h0p;
    float v = half ? bc0[j] : bh0[j];
    #pragma unroll
    for (int s = 0; s < 8; ++s) v += P[(size_t)s * 64 * 512 + i];
    if (half) c[i] = v;
    else      store_pack(hPh, hPl, 16, i >> 9, j, v);
}

// ---------------------------------------------------------------------------
extern "C" void kernel_launch(void* const* d_in, const int* in_sizes, int n_in,
                              void* d_out, int out_size, void* d_ws, size_t ws_size,
                              hipStream_t stream)
{
    const float* features  = (const float*)d_in[0];
    const int*   captions  = (const int*)  d_in[1];
    const float* W_enc_att = (const float*)d_in[2];
    const float* b_enc_att = (const float*)d_in[3];
    const float* W_dec_att = (const float*)d_in[4];
    const float* b_dec_att = (const float*)d_in[5];
    const float* W_full    = (const float*)d_in[6];
    // d_in[7] = b_full : uniform shift -> softmax invariant, unused
    const float* emb       = (const float*)d_in[8];
    const float* W_ih      = (const float*)d_in[9];
    const float* W_hh      = (const float*)d_in[10];
    const float* b_ih      = (const float*)d_in[11];
    const float* b_hh      = (const float*)d_in[12];
    const float* W_init_h  = (const float*)d_in[13];
    const float* b_init_h  = (const float*)d_in[14];
    const float* W_init_c  = (const float*)d_in[15];
    const float* b_init_c  = (const float*)d_in[16];
    const float* W_fbeta   = (const float*)d_in[17];
    const float* b_fbeta   = (const float*)d_in[18];
    const float* W_fc      = (const float*)d_in[19];
    const float* b_fc      = (const float*)d_in[20];
    float* out = (float*)d_out;
    (void)ws_size;

    float* ws = (float*)d_ws;
    size_t off = 0;
    auto alloc  = [&](size_t n) { float* p = ws + off; off += n; return p; };
    auto ualloc = [&](size_t n) { ushort_t* p = (ushort_t*)(ws + off); off += (n + 1) / 2; return p; };

    float* att1   = alloc((size_t)12544 * 512);
    float* eW     = alloc((size_t)64 * 20 * 2048);
    float* mean   = alloc(64 * 2048);
    float* hga    = alloc((size_t)4 * 64 * 4608);
    float* gatesp = alloc((size_t)8 * 64 * 2048);
    float* c      = alloc(64 * 512);
    float* scores = alloc(64 * 196);

    ushort_t* WencH = ualloc((size_t)32 * 64 * 512);   // W_enc_att  (K2048, N512)
    ushort_t* WencL = ualloc((size_t)32 * 64 * 512);
    ushort_t* WtopH = ualloc((size_t)128 * 16 * 512);  // W_ih[:512] (K512, N2048)
    ushort_t* WtopL = ualloc((size_t)128 * 16 * 512);
    ushort_t* Wih2H = ualloc((size_t)128 * 64 * 512);  // W_ih[512:] (K2048, N2048)
    ushort_t* Wih2L = ualloc((size_t)128 * 64 * 512);
    ushort_t* WdfhH = ualloc((size_t)288 * 16 * 512);  // [Wd|Wf|Wh] (K512, N4608)
    ushort_t* WdfhL = ualloc((size_t)288 * 16 * 512);
    ushort_t* WfcH  = ualloc((size_t)632 * 16 * 512);  // W_fc       (K512, N10000->10112)
    ushort_t* WfcL  = ualloc((size_t)632 * 16 * 512);
    ushort_t* embsH = ualloc((size_t)80 * 16 * 512);   // embs  (M1280, K512)
    ushort_t* embsL = ualloc((size_t)80 * 16 * 512);
    ushort_t* hPh   = ualloc((size_t)4 * 16 * 512);    // h     (M64, K512)
    ushort_t* hPl   = ualloc((size_t)4 * 16 * 512);
    ushort_t* gPh   = ualloc((size_t)4 * 64 * 512);    // gated (M64, K2048)
    ushort_t* gPl   = ualloc((size_t)4 * 64 * 512);
    ushort_t* sPh   = ualloc((size_t)80 * 16 * 512);   // hseq  (M1280, K512)
    ushort_t* sPl   = ualloc((size_t)80 * 16 * 512);

    // one-time h0/c0 partials reuse step buffers (consumed before loop)
    float* h0p = hga;      // 8*64*512 <= 4*64*4608
    float* c0p = gatesp;   // 8*64*512 <= 8*64*2048

    // ---- pack weights ----
    pack_b<<<512,  TB, 0, stream>>>(W_enc_att, 512, 32, 64, WencH, WencL, 0);
    pack_b<<<512,  TB, 0, stream>>>(W_ih, 2048, 128, 16, WtopH, WtopL, 0);
    pack_b<<<2048, TB, 0, stream>>>(W_ih + (size_t)512 * 2048, 2048, 128, 64, Wih2H, Wih2L, 0);
    pack_b<<<128,  TB, 0, stream>>>(W_dec_att, 512, 32, 16, WdfhH, WdfhL, 0);
    pack_b<<<512,  TB, 0, stream>>>(W_fbeta, 2048, 128, 16, WdfhH, WdfhL, 32);
    pack_b<<<512,  TB, 0, stream>>>(W_hh, 2048, 128, 16, WdfhH, WdfhL, 160);
    pack_b<<<2528, TB, 0, stream>>>(W_fc, 10000, 632, 16, WfcH, WfcL, 0);

    // ---- precompute (step-invariant) ----
    mean_feat<<<dim3(8, 64), TB, 0, stream>>>(features, mean);
    gather_emb_pack<<<1280, TB, 0, stream>>>(captions, emb, embsH, embsL);
    gemm_part<<<dim3(8, 8), TB, 0, stream>>>(mean, 2048, W_init_h, 512, h0p, 512, 512, 256);
    gemm_part<<<dim3(8, 8), TB, 0, stream>>>(mean, 2048, W_init_c, 512, c0p, 512, 512, 256);
    reduce_hc<<<256, TB, 0, stream>>>(h0p, c0p, b_init_h, b_init_c, hPh, hPl, c);
    // att1 = features @ W_enc_att + b : (12544 x 512), K=2048
    gemm_att1<<<dim3(4, 98), TB, 0, stream>>>(features, WencH, WencL, b_enc_att, att1);
    // eW = embs @ W_ih[:512] + b_ih : (1280 x 2048), K=512
    gemm_mfma<8, 8, 2, 2><<<dim3(16, 10, 1), TB, 0, stream>>>(
        embsH, embsL, WtopH, WtopL, 16, 16, b_ih, eW, 2048, 2048, 0);

    // ---- sequential decode: cooperative kernel (256 blocks = 1/CU) --------
    LoopArgs la;
    la.WdfhH = WdfhH; la.WdfhL = WdfhL;
    la.Wih2H = Wih2H; la.Wih2L = Wih2L;
    la.att1 = att1; la.bd = b_dec_att; la.Wfull = W_full; la.bf = b_fbeta;
    la.b_hh = b_hh; la.eW = eW; la.features = features;
    la.hga = hga; la.gatesp = gatesp; la.scores = scores; la.c = c;
    la.hPh = hPh; la.hPl = hPl; la.gPh = gPh; la.gPl = gPl;
    la.sPh = sPh; la.sPl = sPl;
    void* kargs[] = { (void*)&la };
    hipError_t ce = hipLaunchCooperativeKernel((const void*)loop_mega,
                                               dim3(256), dim3(TB),
                                               kargs, 0, stream);
    if (ce != hipSuccess) {
        // fallback: identical math as discrete launches
        (void)hipGetLastError();
        for (int t = 0; t < 20; ++t) {
            p1_k<<<144, TB, 0, stream>>>(la);
            p2_k<<<256, TB, 0, stream>>>(la);
            p3_k<<<256, TB, 0, stream>>>(la);
            p4_k<<<256, TB, 0, stream>>>(la);
            p5_k<<<128, TB, 0, stream>>>(la, t);
        }
    }

    // preds = hseq @ W_fc + b_fc : (1280 x 10000), K=512
    gemm_mfma<8, 8, 2, 2><<<dim3(79, 10, 1), TB, 0, stream>>>(
        sPh, sPl, WfcH, WfcL, 16, 16, b_fc, out, 10000, 10000, 0);
}

// Round 6
// 1185.906 us; speedup vs baseline: 4.4346x; 4.4346x over previous
//
#include <hip/hip_runtime.h>
#include <hip/hip_bf16.h>

// ---------------------------------------------------------------------------
// Shapes: B=64, P=196, ENC=2048, E=H=A=512, V=10000, L=21 -> T=20
// All GEMMs on MFMA via split-bf16 (hi+lo): C = Ah@Bh + Ah@Bl + Al@Bh.
// Packed fragment layout (16-row tile x 32-k chunk -> 64 lanes x 8 bf16):
//   flat = (((mn>>4)*KC + (k>>5))*64 + ((k&31)>>3)*16 + (mn&15))*8 + (k&7)
// Discrete-launch loop (coop mega-kernel was HBM-latency-bound: 422 GB/s).
// ---------------------------------------------------------------------------

#define TB 256

typedef __bf16 bf16x8 __attribute__((ext_vector_type(8)));
typedef float f32x4 __attribute__((ext_vector_type(4)));
typedef unsigned short u16x8 __attribute__((ext_vector_type(8)));
typedef unsigned short u16x4 __attribute__((ext_vector_type(4)));
typedef unsigned short ushort_t;

__device__ __forceinline__ ushort_t f2bf(float x) {
    unsigned u = __builtin_bit_cast(unsigned, x);
    u += 0x7fffu + ((u >> 16) & 1u);          // round-to-nearest-even
    return (ushort_t)(u >> 16);
}
__device__ __forceinline__ float bf2f(ushort_t b) {
    return __builtin_bit_cast(float, (unsigned)b << 16);
}
__device__ __forceinline__ void store_pack(
    ushort_t* __restrict__ Ph, ushort_t* __restrict__ Pl,
    int KC, int m, int k, float v)
{
    const size_t flat = ((((size_t)(m >> 4) * KC + (k >> 5)) * 64)
                         + ((k & 31) >> 3) * 16 + (m & 15)) * 8 + (k & 7);
    const ushort_t h = f2bf(v);
    Ph[flat] = h;
    Pl[flat] = f2bf(v - bf2f(h));
}

// ------------------------- fused weight pack kernel ------------------------
struct PackJobs {
    const float* W[7];
    ushort_t* Bh[7];
    ushort_t* Bl[7];
    int Nsrc[7], ntCount[7], KC[7], ntBase[7];
    int cum[8];
};

__global__ __launch_bounds__(TB) void pack_all(PackJobs J)
{
    const int blk = blockIdx.x;
    int j = 0;
    #pragma unroll
    for (int i = 1; i < 7; ++i) if (blk >= J.cum[i]) j = i;
    const int g = (blk - J.cum[j]) * TB + threadIdx.x;
    const int KC = J.KC[j];
    const int lane = g & 63;
    const int kc = (g >> 6) % KC;
    const int nt = g / (64 * KC);
    if (nt >= J.ntCount[j]) return;
    const int Nsrc = J.Nsrc[j];
    const float* W = J.W[j];
    const int n = nt * 16 + (lane & 15);
    const int kb = kc * 32 + (lane >> 4) * 8;
    u16x8 hv, lv;
    #pragma unroll
    for (int e = 0; e < 8; ++e) {
        const float x = (n < Nsrc) ? W[(size_t)(kb + e) * Nsrc + n] : 0.f;
        const ushort_t h = f2bf(x);
        hv[e] = h;
        lv[e] = f2bf(x - bf2f(h));
    }
    const size_t flat = (((size_t)(J.ntBase[j] + nt) * KC + kc) * 64 + lane) * 8;
    *(u16x8*)&J.Bh[j][flat] = hv;
    *(u16x8*)&J.Bl[j][flat] = lv;
}

// ------------------------- MFMA tile compute -------------------------------
template<int MT, int NT, int WR, int WC>
__device__ __forceinline__ void mfma_tile(
    const ushort_t* lds, int wr, int wc, int lane,
    f32x4 acc[MT / WR][NT / WC])
{
    constexpr int MFR = MT / WR, NFR = NT / WC;
    bf16x8 ah[MFR], al[MFR];
    #pragma unroll
    for (int i = 0; i < MFR; ++i) {
        ah[i] = __builtin_bit_cast(bf16x8, *(const u16x8*)&lds[(wr * MFR + i) * 512 + lane * 8]);
        al[i] = __builtin_bit_cast(bf16x8, *(const u16x8*)&lds[(MT + wr * MFR + i) * 512 + lane * 8]);
    }
    #pragma unroll
    for (int j = 0; j < NFR; ++j) {
        const bf16x8 bh = __builtin_bit_cast(bf16x8, *(const u16x8*)&lds[(2 * MT + wc * NFR + j) * 512 + lane * 8]);
        const bf16x8 bl = __builtin_bit_cast(bf16x8, *(const u16x8*)&lds[(2 * MT + NT + wc * NFR + j) * 512 + lane * 8]);
        #pragma unroll
        for (int i = 0; i < MFR; ++i) {
            acc[i][j] = __builtin_amdgcn_mfma_f32_16x16x32_bf16(ah[i], bh, acc[i][j], 0, 0, 0);
            acc[i][j] = __builtin_amdgcn_mfma_f32_16x16x32_bf16(ah[i], bl, acc[i][j], 0, 0, 0);
            acc[i][j] = __builtin_amdgcn_mfma_f32_16x16x32_bf16(al[i], bh, acc[i][j], 0, 0, 0);
        }
    }
}

// ------------------------- generic packed MFMA GEMM ------------------------
// XCD-bijective swizzle, nb-major chunking.
template<int MT, int NT, int WR, int WC>
__global__ __launch_bounds__(TB) void gemm_mfma(
    const ushort_t* __restrict__ Ah, const ushort_t* __restrict__ Al,
    const ushort_t* __restrict__ Bh, const ushort_t* __restrict__ Bl,
    int KC, int kcPer,
    const float* __restrict__ bias,
    float* __restrict__ C, int ldc, int Ncols, size_t cPartStride)
{
    constexpr int MFR = MT / WR, NFR = NT / WC, CH = 2 * (MT + NT);
    __shared__ __align__(16) ushort_t lds[CH * 512];
    const int tid = threadIdx.x, wid = tid >> 6, lane = tid & 63;
    const int wr = wid / WC, wc = wid % WC;

    const int tot = gridDim.x * gridDim.y;
    const int lin = blockIdx.x + gridDim.x * blockIdx.y;
    const int q = tot >> 3, r = tot & 7;
    const int xcd = lin & 7, jj = lin >> 3;
    const int base = (xcd < r) ? xcd * (q + 1) : r * (q + 1) + (xcd - r) * q;
    const int lin2 = base + jj;
    const int nb = lin2 / gridDim.y;
    const int mb = lin2 % gridDim.y;

    const int kc0 = blockIdx.z * kcPer;

    f32x4 acc[MFR][NFR];
    #pragma unroll
    for (int i = 0; i < MFR; ++i)
        #pragma unroll
        for (int j = 0; j < NFR; ++j)
            acc[i][j] = f32x4{0.f, 0.f, 0.f, 0.f};

    for (int kc = kc0; kc < kc0 + kcPer; ++kc) {
        __syncthreads();
        #pragma unroll
        for (int cc = 0; cc < CH / 4; ++cc) {
            const int c = cc * 4 + wid;
            const ushort_t* src;
            if (c < MT)                src = Ah + ((size_t)(mb * MT + c) * KC + kc) * 512;
            else if (c < 2 * MT)       src = Al + ((size_t)(mb * MT + c - MT) * KC + kc) * 512;
            else if (c < 2 * MT + NT)  src = Bh + ((size_t)(nb * NT + c - 2 * MT) * KC + kc) * 512;
            else                       src = Bl + ((size_t)(nb * NT + c - 2 * MT - NT) * KC + kc) * 512;
            *(u16x8*)&lds[c * 512 + lane * 8] = *(const u16x8*)(src + lane * 8);
        }
        __syncthreads();
        mfma_tile<MT, NT, WR, WC>(lds, wr, wc, lane, acc);
    }

    C += (size_t)blockIdx.z * cPartStride;
    #pragma unroll
    for (int i = 0; i < MFR; ++i)
        #pragma unroll
        for (int j = 0; j < NFR; ++j) {
            const int col = nb * NT * 16 + (wc * NFR + j) * 16 + (lane & 15);
            if (col < Ncols) {
                const float bv = bias ? bias[col] : 0.f;
                const int rbase = mb * MT * 16 + (wr * MFR + i) * 16 + ((lane >> 4) << 2);
                #pragma unroll
                for (int r2 = 0; r2 < 4; ++r2)
                    C[(size_t)(rbase + r2) * ldc + col] = acc[i][j][r2] + bv;
            }
        }
}

// --------- att1 GEMM: A = fp32 features converted on the fly, MT=4 ---------
// grid (4, 196) = 784 blocks; bijective XCD swizzle: one mb's 4 nb-blocks
// land on one XCD (A rows L2-shared), mb ranges contiguous per XCD.
__global__ __launch_bounds__(TB) void gemm_att1(
    const float* __restrict__ A,
    const ushort_t* __restrict__ Bh, const ushort_t* __restrict__ Bl,
    const float* __restrict__ bias, float* __restrict__ C)
{
    __shared__ __align__(16) ushort_t lds[24 * 512];   // Ah4 Al4 Bh8 Bl8
    const int tid = threadIdx.x, wid = tid >> 6, lane = tid & 63;
    const int wr = wid >> 1, wc = wid & 1;

    const int lin = blockIdx.x + (blockIdx.y << 2);   // 784 = 8 * 98
    const int lin2 = (lin & 7) * 98 + (lin >> 3);
    const int nb = lin2 & 3, mb = lin2 >> 2;          // mb 0..195 (64 rows)

    f32x4 acc[2][4];
    #pragma unroll
    for (int i = 0; i < 2; ++i)
        #pragma unroll
        for (int j = 0; j < 4; ++j)
            acc[i][j] = f32x4{0.f, 0.f, 0.f, 0.f};

    for (int kc = 0; kc < 64; ++kc) {
        __syncthreads();
        // B: 16 chunks (8 hi + 8 lo) -> lds chunks 8..23
        #pragma unroll
        for (int cc = 0; cc < 4; ++cc) {
            const int c = cc * 4 + wid;
            const ushort_t* src = (c < 8)
                ? Bh + ((size_t)(nb * 8 + c) * 64 + kc) * 512
                : Bl + ((size_t)(nb * 8 + c - 8) * 64 + kc) * 512;
            *(u16x8*)&lds[(8 + c) * 512 + lane * 8] = *(const u16x8*)(src + lane * 8);
        }
        // A: 64 rows x 32 k fp32 -> hi chunks 0..3, lo chunks 4..7
        #pragma unroll
        for (int p = 0; p < 2; ++p) {
            const int id = p * 256 + tid;             // 0..511
            const int row = id >> 3, c4 = id & 7;
            const float4 a = *(const float4*)&A[(size_t)(mb * 64 + row) * 2048 + kc * 32 + c4 * 4];
            const float xv[4] = {a.x, a.y, a.z, a.w};
            u16x4 hv, lv;
            #pragma unroll
            for (int qq = 0; qq < 4; ++qq) {
                const ushort_t h = f2bf(xv[qq]);
                hv[qq] = h;
                lv[qq] = f2bf(xv[qq] - bf2f(h));
            }
            const int base = ((c4 >> 1) * 16 + (row & 15)) * 8 + (c4 & 1) * 4;
            const int chunk = row >> 4;               // 0..3
            *(u16x4*)&lds[chunk * 512 + base] = hv;
            *(u16x4*)&lds[(4 + chunk) * 512 + base] = lv;
        }
        __syncthreads();
        mfma_tile<4, 8, 2, 2>(lds, wr, wc, lane, acc);
    }

    #pragma unroll
    for (int i = 0; i < 2; ++i)
        #pragma unroll
        for (int j = 0; j < 4; ++j) {
            const int col = nb * 128 + (wc * 4 + j) * 16 + (lane & 15);
            const float bv = bias[col];
            const int rbase = mb * 64 + (wr * 2 + i) * 16 + ((lane >> 4) << 2);
            #pragma unroll
            for (int r = 0; r < 4; ++r)
                C[(size_t)(rbase + r) * 512 + col] = acc[i][j][r] + bv;
        }
}

// ------------------------- fp32 GEMM (one-time h0/c0 only) -----------------
__device__ __forceinline__ void gemm_body(
    float (*As)[68], float (*Ws)[68],
    const float* __restrict__ A, int lda,
    const float* __restrict__ W, int ldw,
    float* __restrict__ C, int ldc,
    int nTile, int N, int K)
{
    const int tid = threadIdx.x;
    const int tn = tid & 15;
    const int tm = tid >> 4;
    const int n0 = nTile * 64;

    float acc[4][4] = {{0.f}};

    for (int k0 = 0; k0 < K; k0 += 32) {
        {
            int r  = tid >> 3;
            int cc = (tid & 7) * 4;
            #pragma unroll
            for (int rr = 0; rr < 64; rr += 32) {
                const float4 a = *(const float4*)&A[(size_t)(rr + r) * lda + (k0 + cc)];
                As[cc + 0][rr + r] = a.x;
                As[cc + 1][rr + r] = a.y;
                As[cc + 2][rr + r] = a.z;
                As[cc + 3][rr + r] = a.w;
            }
        }
        {
            int r  = tid >> 4;
            int cc = (tid & 15) * 4;
            #pragma unroll
            for (int rr = 0; rr < 32; rr += 16) {
                const float4 w = *(const float4*)&W[(size_t)(k0 + rr + r) * ldw + (n0 + cc)];
                *(float4*)&Ws[rr + r][cc] = w;
            }
        }
        __syncthreads();
        #pragma unroll
        for (int kk = 0; kk < 32; ++kk) {
            const float4 a = *(const float4*)&As[kk][tm * 4];
            const float4 w = *(const float4*)&Ws[kk][tn * 4];
            const float av[4] = {a.x, a.y, a.z, a.w};
            const float wv[4] = {w.x, w.y, w.z, w.w};
            #pragma unroll
            for (int i = 0; i < 4; ++i)
                #pragma unroll
                for (int j = 0; j < 4; ++j)
                    acc[i][j] = fmaf(av[i], wv[j], acc[i][j]);
        }
        __syncthreads();
    }

    #pragma unroll
    for (int i = 0; i < 4; ++i) {
        const int m = tm * 4 + i;
        #pragma unroll
        for (int j = 0; j < 4; ++j)
            C[(size_t)m * ldc + (n0 + tn * 4 + j)] = acc[i][j];
    }
}

// h0 AND c0 partials in one launch: grid (8, 16); y<8 -> h, else c.
__global__ __launch_bounds__(TB) void gemm_hc(
    const float* __restrict__ mean,
    const float* __restrict__ Wh0, const float* __restrict__ Wc0,
    float* __restrict__ h0p, float* __restrict__ c0p)
{
    __shared__ float As[32][68];
    __shared__ float Ws[32][68];
    const int ks = blockIdx.y & 7;
    const int which = blockIdx.y >> 3;
    const float* W = which ? Wc0 : Wh0;
    float* Cp = which ? c0p : h0p;
    gemm_body(As, Ws,
              mean + (size_t)ks * 256, 2048,
              W + (size_t)ks * 256 * 512, 512,
              Cp + (size_t)ks * 64 * 512, 512,
              blockIdx.x, 512, 256);
}

// ------------------------- attention scores (float4) -----------------------
// grid (64, 49): b = bx, p = by*4 + wave
__global__ __launch_bounds__(TB) void scores_k(
    const float* __restrict__ att1,      // (64,196,512)
    const float* __restrict__ hga_part,  // (4,64,4608), att2 = cols 0..511
    const float* __restrict__ bd,        // (512,)
    const float* __restrict__ Wfull,     // (512,)
    float* __restrict__ scores)          // (64,196)
{
    const int b = blockIdx.x;
    const int tid = threadIdx.x;
    const int wave = tid >> 6;
    const int lane = tid & 63;

    __shared__ float a2[512];
    __shared__ float wf[512];

    for (int i = tid; i < 512; i += TB) {
        float v = bd[i];
        #pragma unroll
        for (int s = 0; s < 4; ++s)
            v += hga_part[(size_t)s * 64 * 4608 + (size_t)b * 4608 + i];
        a2[i] = v;
        wf[i] = Wfull[i];
    }
    __syncthreads();

    const int p = blockIdx.y * 4 + wave;
    const float* row = att1 + ((size_t)b * 196 + p) * 512;
    float s = 0.f;
    #pragma unroll
    for (int c = 0; c < 512; c += 256) {
        const int k = c + lane * 4;
        const float4 v = *(const float4*)&row[k];
        const float4 av = *(const float4*)&a2[k];
        const float4 wv = *(const float4*)&wf[k];
        s = fmaf(fmaxf(v.x + av.x, 0.f), wv.x, s);
        s = fmaf(fmaxf(v.y + av.y, 0.f), wv.y, s);
        s = fmaf(fmaxf(v.z + av.z, 0.f), wv.z, s);
        s = fmaf(fmaxf(v.w + av.w, 0.f), wv.w, s);
    }
    #pragma unroll
    for (int o = 32; o; o >>= 1) s += __shfl_xor(s, o);
    if (lane == 0) scores[b * 196 + p] = s;
}

// ---------- softmax + awe (float4, p-split over waves) + gate + pack -------
// grid (8, 64): blockIdx.x = 256-col chunk, blockIdx.y = b.
__global__ __launch_bounds__(TB) void awe_gate(
    const float* __restrict__ scores,    // (64,196)
    const float* __restrict__ features,  // (64,196,2048)
    const float* __restrict__ hga_part,  // (4,64,4608), gpre = cols 512..2559
    const float* __restrict__ bf,        // (2048,)
    ushort_t* __restrict__ gPh, ushort_t* __restrict__ gPl)
{
    const int b = blockIdx.y, chunk = blockIdx.x;
    const int tid = threadIdx.x;
    const int q = tid >> 6, lane = tid & 63;

    __shared__ float al[196];
    __shared__ float redm[4], reds[4];
    __shared__ float smq[4][256];

    const float sv = (tid < 196) ? scores[b * 196 + tid] : -1e30f;
    float m = sv;
    #pragma unroll
    for (int o = 32; o; o >>= 1) m = fmaxf(m, __shfl_xor(m, o));
    if (lane == 0) redm[q] = m;
    __syncthreads();
    m = fmaxf(fmaxf(redm[0], redm[1]), fmaxf(redm[2], redm[3]));

    const float e = (tid < 196) ? expf(sv - m) : 0.f;
    float s = e;
    #pragma unroll
    for (int o = 32; o; o >>= 1) s += __shfl_xor(s, o);
    if (lane == 0) reds[q] = s;
    __syncthreads();
    s = reds[0] + reds[1] + reds[2] + reds[3];

    if (tid < 196) al[tid] = e / s;
    __syncthreads();

    // awe over p in [q*49, q*49+49), float4 cols
    const int col0 = chunk * 256 + lane * 4;
    const float* f = features + (size_t)b * 196 * 2048 + col0;
    f32x4 acc = {0.f, 0.f, 0.f, 0.f};
    const int p0 = q * 49;
    #pragma unroll 7
    for (int pp = 0; pp < 49; ++pp) {
        const float w = al[p0 + pp];
        const float4 v = *(const float4*)&f[(size_t)(p0 + pp) * 2048];
        acc[0] = fmaf(w, v.x, acc[0]);
        acc[1] = fmaf(w, v.y, acc[1]);
        acc[2] = fmaf(w, v.z, acc[2]);
        acc[3] = fmaf(w, v.w, acc[3]);
    }
    *(f32x4*)&smq[q][lane * 4] = acc;
    __syncthreads();

    const int eg = chunk * 256 + tid;
    const float a = smq[0][tid] + smq[1][tid] + smq[2][tid] + smq[3][tid];
    float gp = bf[eg];
    #pragma unroll
    for (int ss = 0; ss < 4; ++ss)
        gp += hga_part[(size_t)ss * 64 * 4608 + (size_t)b * 4608 + 512 + eg];
    const float gate = 1.f / (1.f + expf(-gp));
    store_pack(gPh, gPl, 64, b, eg, gate * a);
}

// ------------------------- LSTM pointwise ----------------------------------
__global__ __launch_bounds__(TB) void lstm_pw(
    const float* __restrict__ gates_part,  // (8,64,2048)
    const float* __restrict__ hga_part,    // (4,64,4608), gh = cols 2560..4607
    const float* __restrict__ eW,          // (64,20,2048), includes b_ih
    const float* __restrict__ b_hh,        // (2048,)
    int t,
    float* __restrict__ c,                 // (64,512)
    ushort_t* __restrict__ hPh, ushort_t* __restrict__ hPl,
    ushort_t* __restrict__ sPh, ushort_t* __restrict__ sPl)
{
    const int idx = blockIdx.x * TB + threadIdx.x;   // 0..32767
    const int b = idx >> 9;
    const int j = idx & 511;

    float g[4];
    #pragma unroll
    for (int comp = 0; comp < 4; ++comp) {
        const int col = comp * 512 + j;
        float v = b_hh[col] + eW[((size_t)b * 20 + t) * 2048 + col];
        #pragma unroll
        for (int s = 0; s < 8; ++s)
            v += gates_part[(size_t)s * 64 * 2048 + (size_t)b * 2048 + col];
        #pragma unroll
        for (int s = 0; s < 4; ++s)
            v += hga_part[(size_t)s * 64 * 4608 + (size_t)b * 4608 + 2560 + col];
        g[comp] = v;
    }
    const float si = 1.f / (1.f + expf(-g[0]));
    const float sf = 1.f / (1.f + expf(-g[1]));
    const float gg = tanhf(g[2]);
    const float so = 1.f / (1.f + expf(-g[3]));
    const float cn = sf * c[idx] + si * gg;
    c[idx] = cn;
    const float hn = so * tanhf(cn);
    store_pack(hPh, hPl, 16, b, j, hn);
    store_pack(sPh, sPl, 16, b * 20 + t, j, hn);
}

// ------------------------- precompute helpers ------------------------------
__global__ __launch_bounds__(TB) void mean_feat(
    const float* __restrict__ features, float* __restrict__ mean_enc)
{
    const int b = blockIdx.y;
    const int e = blockIdx.x * TB + threadIdx.x;
    const float* f = features + (size_t)b * 196 * 2048 + e;
    float s = 0.f;
    #pragma unroll 4
    for (int p = 0; p < 196; ++p) s += f[(size_t)p * 2048];
    mean_enc[b * 2048 + e] = s * (1.f / 196.f);
}

__global__ __launch_bounds__(TB) void gather_emb_pack(
    const int* __restrict__ captions,
    const float* __restrict__ emb,
    ushort_t* __restrict__ Ph, ushort_t* __restrict__ Pl)
{
    const int bt = blockIdx.x;          // 0..1279
    const int b = bt / 20;
    const int t = bt % 20;
    const int tok = captions[b * 21 + t];
    for (int e = threadIdx.x; e < 512; e += TB)
        store_pack(Ph, Pl, 16, bt, e, emb[(size_t)tok * 512 + e]);
}

__global__ __launch_bounds__(TB) void reduce_hc(
    const float* __restrict__ h0p, const float* __restrict__ c0p,
    const float* __restrict__ bh0, const float* __restrict__ bc0,
    ushort_t* __restrict__ hPh, ushort_t* __restrict__ hPl,
    float* __restrict__ c)
{
    const int idx = blockIdx.x * TB + threadIdx.x;   // 0..65535
    const int half = idx >> 15;
    const int i = idx & 32767;
    const int j = i & 511;
    const float* P = half ? c0p : h0p;
    float v = half ? bc0[j] : bh0[j];
    #pragma unroll
    for (int s = 0; s < 8; ++s) v += P[(size_t)s * 64 * 512 + i];
    if (half) c[i] = v;
    else      store_pack(hPh, hPl, 16, i >> 9, j, v);
}

// ---------------------------------------------------------------------------
extern "C" void kernel_launch(void* const* d_in, const int* in_sizes, int n_in,
                              void* d_out, int out_size, void* d_ws, size_t ws_size,
                              hipStream_t stream)
{
    const float* features  = (const float*)d_in[0];
    const int*   captions  = (const int*)  d_in[1];
    const float* W_enc_att = (const float*)d_in[2];
    const float* b_enc_att = (const float*)d_in[3];
    const float* W_dec_att = (const float*)d_in[4];
    const float* b_dec_att = (const float*)d_in[5];
    const float* W_full    = (const float*)d_in[6];
    // d_in[7] = b_full : uniform shift -> softmax invariant, unused
    const float* emb       = (const float*)d_in[8];
    const float* W_ih      = (const float*)d_in[9];
    const float* W_hh      = (const float*)d_in[10];
    const float* b_ih      = (const float*)d_in[11];
    const float* b_hh      = (const float*)d_in[12];
    const float* W_init_h  = (const float*)d_in[13];
    const float* b_init_h  = (const float*)d_in[14];
    const float* W_init_c  = (const float*)d_in[15];
    const float* b_init_c  = (const float*)d_in[16];
    const float* W_fbeta   = (const float*)d_in[17];
    const float* b_fbeta   = (const float*)d_in[18];
    const float* W_fc      = (const float*)d_in[19];
    const float* b_fc      = (const float*)d_in[20];
    float* out = (float*)d_out;
    (void)ws_size;

    float* ws = (float*)d_ws;
    size_t off = 0;
    auto alloc  = [&](size_t n) { float* p = ws + off; off += n; return p; };
    auto ualloc = [&](size_t n) { ushort_t* p = (ushort_t*)(ws + off); off += (n + 1) / 2; return p; };

    float* att1   = alloc((size_t)12544 * 512);
    float* eW     = alloc((size_t)64 * 20 * 2048);
    float* mean   = alloc(64 * 2048);
    float* hga    = alloc((size_t)4 * 64 * 4608);
    float* gatesp = alloc((size_t)8 * 64 * 2048);
    float* c      = alloc(64 * 512);
    float* scores = alloc(64 * 196);

    ushort_t* WencH = ualloc((size_t)32 * 64 * 512);   // W_enc_att  (K2048, N512)
    ushort_t* WencL = ualloc((size_t)32 * 64 * 512);
    ushort_t* WtopH = ualloc((size_t)128 * 16 * 512);  // W_ih[:512] (K512, N2048)
    ushort_t* WtopL = ualloc((size_t)128 * 16 * 512);
    ushort_t* Wih2H = ualloc((size_t)128 * 64 * 512);  // W_ih[512:] (K2048, N2048)
    ushort_t* Wih2L = ualloc((size_t)128 * 64 * 512);
    ushort_t* WdfhH = ualloc((size_t)288 * 16 * 512);  // [Wd|Wf|Wh] (K512, N4608)
    ushort_t* WdfhL = ualloc((size_t)288 * 16 * 512);
    ushort_t* WfcH  = ualloc((size_t)632 * 16 * 512);  // W_fc       (K512, N10000->10112)
    ushort_t* WfcL  = ualloc((size_t)632 * 16 * 512);
    ushort_t* embsH = ualloc((size_t)80 * 16 * 512);   // embs  (M1280, K512)
    ushort_t* embsL = ualloc((size_t)80 * 16 * 512);
    ushort_t* hPh   = ualloc((size_t)4 * 16 * 512);    // h     (M64, K512)
    ushort_t* hPl   = ualloc((size_t)4 * 16 * 512);
    ushort_t* gPh   = ualloc((size_t)4 * 64 * 512);    // gated (M64, K2048)
    ushort_t* gPl   = ualloc((size_t)4 * 64 * 512);
    ushort_t* sPh   = ualloc((size_t)80 * 16 * 512);   // hseq  (M1280, K512)
    ushort_t* sPl   = ualloc((size_t)80 * 16 * 512);

    // one-time h0/c0 partials reuse step buffers (consumed before loop)
    float* h0p = hga;      // 8*64*512 <= 4*64*4608
    float* c0p = gatesp;   // 8*64*512 <= 8*64*2048

    // ---- pack all weights in ONE kernel ----
    PackJobs J;
    J.W[0]=W_enc_att;               J.Bh[0]=WencH; J.Bl[0]=WencL; J.Nsrc[0]=512;   J.ntCount[0]=32;  J.KC[0]=64; J.ntBase[0]=0;
    J.W[1]=W_ih;                    J.Bh[1]=WtopH; J.Bl[1]=WtopL; J.Nsrc[1]=2048;  J.ntCount[1]=128; J.KC[1]=16; J.ntBase[1]=0;
    J.W[2]=W_ih + (size_t)512*2048; J.Bh[2]=Wih2H; J.Bl[2]=Wih2L; J.Nsrc[2]=2048;  J.ntCount[2]=128; J.KC[2]=64; J.ntBase[2]=0;
    J.W[3]=W_dec_att;               J.Bh[3]=WdfhH; J.Bl[3]=WdfhL; J.Nsrc[3]=512;   J.ntCount[3]=32;  J.KC[3]=16; J.ntBase[3]=0;
    J.W[4]=W_fbeta;                 J.Bh[4]=WdfhH; J.Bl[4]=WdfhL; J.Nsrc[4]=2048;  J.ntCount[4]=128; J.KC[4]=16; J.ntBase[4]=32;
    J.W[5]=W_hh;                    J.Bh[5]=WdfhH; J.Bl[5]=WdfhL; J.Nsrc[5]=2048;  J.ntCount[5]=128; J.KC[5]=16; J.ntBase[5]=160;
    J.W[6]=W_fc;                    J.Bh[6]=WfcH;  J.Bl[6]=WfcL;  J.Nsrc[6]=10000; J.ntCount[6]=632; J.KC[6]=16; J.ntBase[6]=0;
    {
        int cum = 0;
        const int blks[7] = {512, 512, 2048, 128, 512, 512, 2528};
        for (int i = 0; i < 7; ++i) { J.cum[i] = cum; cum += blks[i]; }
        J.cum[7] = cum;
        pack_all<<<cum, TB, 0, stream>>>(J);
    }

    // ---- precompute (step-invariant) ----
    gather_emb_pack<<<1280, TB, 0, stream>>>(captions, emb, embsH, embsL);
    mean_feat<<<dim3(8, 64), TB, 0, stream>>>(features, mean);
    gemm_hc<<<dim3(8, 16), TB, 0, stream>>>(mean, W_init_h, W_init_c, h0p, c0p);
    reduce_hc<<<256, TB, 0, stream>>>(h0p, c0p, b_init_h, b_init_c, hPh, hPl, c);
    // att1 = features @ W_enc_att + b : (12544 x 512), K=2048
    gemm_att1<<<dim3(4, 196), TB, 0, stream>>>(features, WencH, WencL, b_enc_att, att1);
    // eW = embs @ W_ih[:512] + b_ih : (1280 x 2048), K=512
    gemm_mfma<8, 8, 2, 2><<<dim3(16, 10, 1), TB, 0, stream>>>(
        embsH, embsL, WtopH, WtopL, 16, 16, b_ih, eW, 2048, 2048, 0);

    // ---- sequential decode (discrete launches; proven structure) ----
    for (int t = 0; t < 20; ++t) {
        // hga[ks] = h @ [Wd|Wf|Wh] partials : (64 x 4608), K=512 split 4
        gemm_mfma<4, 8, 2, 2><<<dim3(36, 1, 4), TB, 0, stream>>>(
            hPh, hPl, WdfhH, WdfhL, 16, 4, nullptr, hga, 4608, 4608, (size_t)64 * 4608);
        scores_k<<<dim3(64, 49), TB, 0, stream>>>(att1, hga, b_dec_att, W_full, scores);
        awe_gate<<<dim3(8, 64), TB, 0, stream>>>(scores, features, hga, b_fbeta, gPh, gPl);
        // gatesp[ks] = gated @ W_ih[512:] partials : (64 x 2048), K=2048 split 8
        gemm_mfma<4, 8, 2, 2><<<dim3(16, 1, 8), TB, 0, stream>>>(
            gPh, gPl, Wih2H, Wih2L, 64, 8, nullptr, gatesp, 2048, 2048, (size_t)64 * 2048);
        lstm_pw<<<128, TB, 0, stream>>>(gatesp, hga, eW, b_hh, t, c, hPh, hPl, sPh, sPl);
    }

    // preds = hseq @ W_fc + b_fc : (1280 x 10000), K=512
    gemm_mfma<8, 8, 2, 2><<<dim3(79, 10, 1), TB, 0, stream>>>(
        sPh, sPl, WfcH, WfcL, 16, 16, b_fc, out, 10000, 10000, 0);
}

// Round 7
// 1055.830 us; speedup vs baseline: 4.9809x; 1.1232x over previous
//
#include <hip/hip_runtime.h>
#include <hip/hip_bf16.h>

// ---------------------------------------------------------------------------
// Shapes: B=64, P=196, ENC=2048, E=H=A=512, V=10000, L=21 -> T=20
// GEMMs on MFMA via split-bf16 (hi+lo): C = Ah@Bh + Ah@Bl (+ Al@Bh where A
// keeps an fp32-accuracy path). features and att1 are held in bf16 to halve
// the loop's per-step bytes and make the working set L3-resident.
// Packed fragment layout (16-row tile x 32-k chunk -> 64 lanes x 8 bf16):
//   flat = (((mn>>4)*KC + (k>>5))*64 + ((k&31)>>3)*16 + (mn&15))*8 + (k&7)
// ---------------------------------------------------------------------------

#define TB 256

typedef __bf16 bf16x8 __attribute__((ext_vector_type(8)));
typedef float f32x4 __attribute__((ext_vector_type(4)));
typedef unsigned short u16x8 __attribute__((ext_vector_type(8)));
typedef unsigned short u16x4 __attribute__((ext_vector_type(4)));
typedef unsigned short ushort_t;

__device__ __forceinline__ ushort_t f2bf(float x) {
    unsigned u = __builtin_bit_cast(unsigned, x);
    u += 0x7fffu + ((u >> 16) & 1u);          // round-to-nearest-even
    return (ushort_t)(u >> 16);
}
__device__ __forceinline__ float bf2f(ushort_t b) {
    return __builtin_bit_cast(float, (unsigned)b << 16);
}
__device__ __forceinline__ void store_pack(
    ushort_t* __restrict__ Ph, ushort_t* __restrict__ Pl,
    int KC, int m, int k, float v)
{
    const size_t flat = ((((size_t)(m >> 4) * KC + (k >> 5)) * 64)
                         + ((k & 31) >> 3) * 16 + (m & 15)) * 8 + (k & 7);
    const ushort_t h = f2bf(v);
    Ph[flat] = h;
    Pl[flat] = f2bf(v - bf2f(h));
}

// ------------------------- fused weight pack kernel ------------------------
struct PackJobs {
    const float* W[7];
    ushort_t* Bh[7];
    ushort_t* Bl[7];
    int Nsrc[7], ntCount[7], KC[7], ntBase[7];
    int cum[8];
};

__global__ __launch_bounds__(TB) void pack_all(PackJobs J)
{
    const int blk = blockIdx.x;
    int j = 0;
    #pragma unroll
    for (int i = 1; i < 7; ++i) if (blk >= J.cum[i]) j = i;
    const int g = (blk - J.cum[j]) * TB + threadIdx.x;
    const int KC = J.KC[j];
    const int lane = g & 63;
    const int kc = (g >> 6) % KC;
    const int nt = g / (64 * KC);
    if (nt >= J.ntCount[j]) return;
    const int Nsrc = J.Nsrc[j];
    const float* W = J.W[j];
    const int n = nt * 16 + (lane & 15);
    const int kb = kc * 32 + (lane >> 4) * 8;
    u16x8 hv, lv;
    #pragma unroll
    for (int e = 0; e < 8; ++e) {
        const float x = (n < Nsrc) ? W[(size_t)(kb + e) * Nsrc + n] : 0.f;
        const ushort_t h = f2bf(x);
        hv[e] = h;
        lv[e] = f2bf(x - bf2f(h));
    }
    const size_t flat = (((size_t)(J.ntBase[j] + nt) * KC + kc) * 64 + lane) * 8;
    *(u16x8*)&J.Bh[j][flat] = hv;
    *(u16x8*)&J.Bl[j][flat] = lv;
}

// ------------------------- features fp32 -> bf16 cast ----------------------
// 12544 blocks, 8 elems/thread, fully coalesced.
__global__ __launch_bounds__(TB) void feat2bf(
    const float* __restrict__ f, ushort_t* __restrict__ fbf)
{
    const size_t i8 = ((size_t)blockIdx.x * TB + threadIdx.x) * 8;
    const float4 a = *(const float4*)&f[i8];
    const float4 b = *(const float4*)&f[i8 + 4];
    u16x8 v;
    v[0] = f2bf(a.x); v[1] = f2bf(a.y); v[2] = f2bf(a.z); v[3] = f2bf(a.w);
    v[4] = f2bf(b.x); v[5] = f2bf(b.y); v[6] = f2bf(b.z); v[7] = f2bf(b.w);
    *(u16x8*)&fbf[i8] = v;
}

// ------------------------- MFMA tile compute (A split hi/lo) ---------------
template<int MT, int NT, int WR, int WC>
__device__ __forceinline__ void mfma_tile(
    const ushort_t* lds, int wr, int wc, int lane,
    f32x4 acc[MT / WR][NT / WC])
{
    constexpr int MFR = MT / WR, NFR = NT / WC;
    bf16x8 ah[MFR], al[MFR];
    #pragma unroll
    for (int i = 0; i < MFR; ++i) {
        ah[i] = __builtin_bit_cast(bf16x8, *(const u16x8*)&lds[(wr * MFR + i) * 512 + lane * 8]);
        al[i] = __builtin_bit_cast(bf16x8, *(const u16x8*)&lds[(MT + wr * MFR + i) * 512 + lane * 8]);
    }
    #pragma unroll
    for (int j = 0; j < NFR; ++j) {
        const bf16x8 bh = __builtin_bit_cast(bf16x8, *(const u16x8*)&lds[(2 * MT + wc * NFR + j) * 512 + lane * 8]);
        const bf16x8 bl = __builtin_bit_cast(bf16x8, *(const u16x8*)&lds[(2 * MT + NT + wc * NFR + j) * 512 + lane * 8]);
        #pragma unroll
        for (int i = 0; i < MFR; ++i) {
            acc[i][j] = __builtin_amdgcn_mfma_f32_16x16x32_bf16(ah[i], bh, acc[i][j], 0, 0, 0);
            acc[i][j] = __builtin_amdgcn_mfma_f32_16x16x32_bf16(ah[i], bl, acc[i][j], 0, 0, 0);
            acc[i][j] = __builtin_amdgcn_mfma_f32_16x16x32_bf16(al[i], bh, acc[i][j], 0, 0, 0);
        }
    }
}

// ------------------------- generic packed MFMA GEMM ------------------------
template<int MT, int NT, int WR, int WC>
__global__ __launch_bounds__(TB) void gemm_mfma(
    const ushort_t* __restrict__ Ah, const ushort_t* __restrict__ Al,
    const ushort_t* __restrict__ Bh, const ushort_t* __restrict__ Bl,
    int KC, int kcPer,
    const float* __restrict__ bias,
    float* __restrict__ C, int ldc, int Ncols, size_t cPartStride)
{
    constexpr int MFR = MT / WR, NFR = NT / WC, CH = 2 * (MT + NT);
    __shared__ __align__(16) ushort_t lds[CH * 512];
    const int tid = threadIdx.x, wid = tid >> 6, lane = tid & 63;
    const int wr = wid / WC, wc = wid % WC;

    const int tot = gridDim.x * gridDim.y;
    const int lin = blockIdx.x + gridDim.x * blockIdx.y;
    const int q = tot >> 3, r = tot & 7;
    const int xcd = lin & 7, jj = lin >> 3;
    const int base = (xcd < r) ? xcd * (q + 1) : r * (q + 1) + (xcd - r) * q;
    const int lin2 = base + jj;
    const int nb = lin2 / gridDim.y;
    const int mb = lin2 % gridDim.y;

    const int kc0 = blockIdx.z * kcPer;

    f32x4 acc[MFR][NFR];
    #pragma unroll
    for (int i = 0; i < MFR; ++i)
        #pragma unroll
        for (int j = 0; j < NFR; ++j)
            acc[i][j] = f32x4{0.f, 0.f, 0.f, 0.f};

    for (int kc = kc0; kc < kc0 + kcPer; ++kc) {
        __syncthreads();
        #pragma unroll
        for (int cc = 0; cc < CH / 4; ++cc) {
            const int c = cc * 4 + wid;
            const ushort_t* src;
            if (c < MT)                src = Ah + ((size_t)(mb * MT + c) * KC + kc) * 512;
            else if (c < 2 * MT)       src = Al + ((size_t)(mb * MT + c - MT) * KC + kc) * 512;
            else if (c < 2 * MT + NT)  src = Bh + ((size_t)(nb * NT + c - 2 * MT) * KC + kc) * 512;
            else                       src = Bl + ((size_t)(nb * NT + c - 2 * MT - NT) * KC + kc) * 512;
            *(u16x8*)&lds[c * 512 + lane * 8] = *(const u16x8*)(src + lane * 8);
        }
        __syncthreads();
        mfma_tile<MT, NT, WR, WC>(lds, wr, wc, lane, acc);
    }

    C += (size_t)blockIdx.z * cPartStride;
    #pragma unroll
    for (int i = 0; i < MFR; ++i)
        #pragma unroll
        for (int j = 0; j < NFR; ++j) {
            const int col = nb * NT * 16 + (wc * NFR + j) * 16 + (lane & 15);
            if (col < Ncols) {
                const float bv = bias ? bias[col] : 0.f;
                const int rbase = mb * MT * 16 + (wr * MFR + i) * 16 + ((lane >> 4) << 2);
                #pragma unroll
                for (int r2 = 0; r2 < 4; ++r2)
                    C[(size_t)(rbase + r2) * ldc + col] = acc[i][j][r2] + bv;
            }
        }
}

// --------- att1 GEMM: A = bf16 features (hi only), B split hi/lo -----------
// grid (4, 196); out = bf16 att1 (+bias). LDS: A 4 chunks, Bh 8, Bl 8 = 20KB.
__global__ __launch_bounds__(TB) void gemm_att1(
    const ushort_t* __restrict__ fbf,
    const ushort_t* __restrict__ Bh, const ushort_t* __restrict__ Bl,
    const float* __restrict__ bias, ushort_t* __restrict__ att1bf)
{
    __shared__ __align__(16) ushort_t lds[20 * 512];
    const int tid = threadIdx.x, wid = tid >> 6, lane = tid & 63;
    const int wr = wid >> 1, wc = wid & 1;

    const int lin = blockIdx.x + (blockIdx.y << 2);   // 784 = 8 * 98
    const int lin2 = (lin & 7) * 98 + (lin >> 3);
    const int nb = lin2 & 3, mb = lin2 >> 2;          // mb 0..195 (64 rows)

    f32x4 acc[2][4];
    #pragma unroll
    for (int i = 0; i < 2; ++i)
        #pragma unroll
        for (int j = 0; j < 4; ++j)
            acc[i][j] = f32x4{0.f, 0.f, 0.f, 0.f};

    const int arow = tid >> 2, akg = tid & 3;         // A-stage mapping
    const size_t abase = (size_t)(mb * 64 + arow) * 2048 + akg * 8;
    const int aldst = (arow >> 4) * 512 + (akg * 16 + (arow & 15)) * 8;

    for (int kc = 0; kc < 64; ++kc) {
        __syncthreads();
        // B: 16 chunks (8 hi + 8 lo) -> lds chunks 4..19
        #pragma unroll
        for (int cc = 0; cc < 4; ++cc) {
            const int c = cc * 4 + wid;
            const ushort_t* src = (c < 8)
                ? Bh + ((size_t)(nb * 8 + c) * 64 + kc) * 512
                : Bl + ((size_t)(nb * 8 + c - 8) * 64 + kc) * 512;
            *(u16x8*)&lds[(4 + c) * 512 + lane * 8] = *(const u16x8*)(src + lane * 8);
        }
        // A: 64 rows x 32 k bf16 -> chunks 0..3 (pure 16B copies)
        *(u16x8*)&lds[aldst] = *(const u16x8*)&fbf[abase + (size_t)kc * 32];
        __syncthreads();

        // MFMA: acc += Ah*Bh + Ah*Bl
        bf16x8 ah[2];
        #pragma unroll
        for (int i = 0; i < 2; ++i)
            ah[i] = __builtin_bit_cast(bf16x8, *(const u16x8*)&lds[(wr * 2 + i) * 512 + lane * 8]);
        #pragma unroll
        for (int j = 0; j < 4; ++j) {
            const bf16x8 bh = __builtin_bit_cast(bf16x8, *(const u16x8*)&lds[(4 + wc * 4 + j) * 512 + lane * 8]);
            const bf16x8 bl = __builtin_bit_cast(bf16x8, *(const u16x8*)&lds[(12 + wc * 4 + j) * 512 + lane * 8]);
            #pragma unroll
            for (int i = 0; i < 2; ++i) {
                acc[i][j] = __builtin_amdgcn_mfma_f32_16x16x32_bf16(ah[i], bh, acc[i][j], 0, 0, 0);
                acc[i][j] = __builtin_amdgcn_mfma_f32_16x16x32_bf16(ah[i], bl, acc[i][j], 0, 0, 0);
            }
        }
    }

    #pragma unroll
    for (int i = 0; i < 2; ++i)
        #pragma unroll
        for (int j = 0; j < 4; ++j) {
            const int col = nb * 128 + (wc * 4 + j) * 16 + (lane & 15);
            const float bv = bias[col];
            const int rbase = mb * 64 + (wr * 2 + i) * 16 + ((lane >> 4) << 2);
            #pragma unroll
            for (int r = 0; r < 4; ++r)
                att1bf[(size_t)(rbase + r) * 512 + col] = f2bf(acc[i][j][r] + bv);
        }
}

// ------------------------- fp32 GEMM (one-time h0/c0 only) -----------------
__device__ __forceinline__ void gemm_body(
    float (*As)[68], float (*Ws)[68],
    const float* __restrict__ A, int lda,
    const float* __restrict__ W, int ldw,
    float* __restrict__ C, int ldc,
    int nTile, int N, int K)
{
    const int tid = threadIdx.x;
    const int tn = tid & 15;
    const int tm = tid >> 4;
    const int n0 = nTile * 64;

    float acc[4][4] = {{0.f}};

    for (int k0 = 0; k0 < K; k0 += 32) {
        {
            int r  = tid >> 3;
            int cc = (tid & 7) * 4;
            #pragma unroll
            for (int rr = 0; rr < 64; rr += 32) {
                const float4 a = *(const float4*)&A[(size_t)(rr + r) * lda + (k0 + cc)];
                As[cc + 0][rr + r] = a.x;
                As[cc + 1][rr + r] = a.y;
                As[cc + 2][rr + r] = a.z;
                As[cc + 3][rr + r] = a.w;
            }
        }
        {
            int r  = tid >> 4;
            int cc = (tid & 15) * 4;
            #pragma unroll
            for (int rr = 0; rr < 32; rr += 16) {
                const float4 w = *(const float4*)&W[(size_t)(k0 + rr + r) * ldw + (n0 + cc)];
                *(float4*)&Ws[rr + r][cc] = w;
            }
        }
        __syncthreads();
        #pragma unroll
        for (int kk = 0; kk < 32; ++kk) {
            const float4 a = *(const float4*)&As[kk][tm * 4];
            const float4 w = *(const float4*)&Ws[kk][tn * 4];
            const float av[4] = {a.x, a.y, a.z, a.w};
            const float wv[4] = {w.x, w.y, w.z, w.w};
            #pragma unroll
            for (int i = 0; i < 4; ++i)
                #pragma unroll
                for (int j = 0; j < 4; ++j)
                    acc[i][j] = fmaf(av[i], wv[j], acc[i][j]);
        }
        __syncthreads();
    }

    #pragma unroll
    for (int i = 0; i < 4; ++i) {
        const int m = tm * 4 + i;
        #pragma unroll
        for (int j = 0; j < 4; ++j)
            C[(size_t)m * ldc + (n0 + tn * 4 + j)] = acc[i][j];
    }
}

__global__ __launch_bounds__(TB) void gemm_hc(
    const float* __restrict__ mean,
    const float* __restrict__ Wh0, const float* __restrict__ Wc0,
    float* __restrict__ h0p, float* __restrict__ c0p)
{
    __shared__ float As[32][68];
    __shared__ float Ws[32][68];
    const int ks = blockIdx.y & 7;
    const int which = blockIdx.y >> 3;
    const float* W = which ? Wc0 : Wh0;
    float* Cp = which ? c0p : h0p;
    gemm_body(As, Ws,
              mean + (size_t)ks * 256, 2048,
              W + (size_t)ks * 256 * 512, 512,
              Cp + (size_t)ks * 64 * 512, 512,
              blockIdx.x, 512, 256);
}

// ------------------------- attention scores (bf16 att1) --------------------
// grid (64, 7): b = bx, wave handles 7 p's; a2/wf hoisted to registers.
__global__ __launch_bounds__(TB) void scores_k(
    const ushort_t* __restrict__ att1bf,  // (64,196,512) bf16
    const float* __restrict__ hga_part,   // (4,64,4608), att2 = cols 0..511
    const float* __restrict__ bd,         // (512,)
    const float* __restrict__ Wfull,      // (512,)
    float* __restrict__ scores)           // (64,196)
{
    const int b = blockIdx.x;
    const int tid = threadIdx.x;
    const int wave = tid >> 6;
    const int lane = tid & 63;

    __shared__ float a2[512];
    __shared__ float wf[512];

    for (int i = tid; i < 512; i += TB) {
        float v = bd[i];
        #pragma unroll
        for (int s = 0; s < 4; ++s)
            v += hga_part[(size_t)s * 64 * 4608 + (size_t)b * 4608 + i];
        a2[i] = v;
        wf[i] = Wfull[i];
    }
    __syncthreads();

    const int k0 = lane * 8;
    float a2r[8], wfr[8];
    #pragma unroll
    for (int e = 0; e < 8; ++e) { a2r[e] = a2[k0 + e]; wfr[e] = wf[k0 + e]; }

    const int p0 = blockIdx.y * 28 + wave * 7;
    #pragma unroll
    for (int pp = 0; pp < 7; ++pp) {
        const int p = p0 + pp;
        const u16x8 v = *(const u16x8*)&att1bf[((size_t)b * 196 + p) * 512 + k0];
        float s = 0.f;
        #pragma unroll
        for (int e = 0; e < 8; ++e)
            s = fmaf(fmaxf(bf2f(v[e]) + a2r[e], 0.f), wfr[e], s);
        #pragma unroll
        for (int o = 32; o; o >>= 1) s += __shfl_xor(s, o);
        if (lane == 0) scores[b * 196 + p] = s;
    }
}

// ---------- softmax + awe (bf16 features) + gate + pack --------------------
// grid (4, 64), 512 threads: 8 waves x ~25 p's, lane covers 8 cols (u16x8).
__global__ __launch_bounds__(512) void awe_gate(
    const float* __restrict__ scores,     // (64,196)
    const ushort_t* __restrict__ fbf,     // (64,196,2048) bf16
    const float* __restrict__ hga_part,   // (4,64,4608), gpre = cols 512..2559
    const float* __restrict__ bf,         // (2048,)
    ushort_t* __restrict__ gPh, ushort_t* __restrict__ gPl)
{
    const int b = blockIdx.y, chunk = blockIdx.x;
    const int tid = threadIdx.x;
    const int q = tid >> 6, lane = tid & 63;

    __shared__ float al[196];
    __shared__ float redm[8], reds[8];
    __shared__ float smq[8][512];

    const float sv = (tid < 196) ? scores[b * 196 + tid] : -1e30f;
    float m = sv;
    #pragma unroll
    for (int o = 32; o; o >>= 1) m = fmaxf(m, __shfl_xor(m, o));
    if (lane == 0) redm[q] = m;
    __syncthreads();
    m = redm[0];
    #pragma unroll
    for (int i = 1; i < 8; ++i) m = fmaxf(m, redm[i]);

    const float e = (tid < 196) ? expf(sv - m) : 0.f;
    float s = e;
    #pragma unroll
    for (int o = 32; o; o >>= 1) s += __shfl_xor(s, o);
    if (lane == 0) reds[q] = s;
    __syncthreads();
    s = reds[0];
    #pragma unroll
    for (int i = 1; i < 8; ++i) s += reds[i];

    if (tid < 196) al[tid] = e / s;
    __syncthreads();

    // awe: wave q covers p in [q*25, min(q*25+25,196)), lane covers 8 cols
    const int col0 = chunk * 512 + lane * 8;
    const ushort_t* f = fbf + (size_t)b * 196 * 2048 + col0;
    float acc[8] = {0.f, 0.f, 0.f, 0.f, 0.f, 0.f, 0.f, 0.f};
    const int p0 = q * 25;
    const int pn = (q == 7) ? 21 : 25;
    for (int pp = 0; pp < pn; ++pp) {
        const float w = al[p0 + pp];
        const u16x8 v = *(const u16x8*)&f[(size_t)(p0 + pp) * 2048];
        #pragma unroll
        for (int ee = 0; ee < 8; ++ee)
            acc[ee] = fmaf(w, bf2f(v[ee]), acc[ee]);
    }
    *(f32x4*)&smq[q][lane * 8]     = f32x4{acc[0], acc[1], acc[2], acc[3]};
    *(f32x4*)&smq[q][lane * 8 + 4] = f32x4{acc[4], acc[5], acc[6], acc[7]};
    __syncthreads();

    const int eg = chunk * 512 + tid;
    float a = smq[0][tid];
    #pragma unroll
    for (int i = 1; i < 8; ++i) a += smq[i][tid];
    float gp = bf[eg];
    #pragma unroll
    for (int ss = 0; ss < 4; ++ss)
        gp += hga_part[(size_t)ss * 64 * 4608 + (size_t)b * 4608 + 512 + eg];
    const float gate = 1.f / (1.f + expf(-gp));
    store_pack(gPh, gPl, 64, b, eg, gate * a);
}

// ------------------------- LSTM pointwise ----------------------------------
__global__ __launch_bounds__(TB) void lstm_pw(
    const float* __restrict__ gates_part,  // (8,64,2048)
    const float* __restrict__ hga_part,    // (4,64,4608), gh = cols 2560..4607
    const float* __restrict__ eW,          // (64,20,2048), includes b_ih
    const float* __restrict__ b_hh,        // (2048,)
    int t,
    float* __restrict__ c,                 // (64,512)
    ushort_t* __restrict__ hPh, ushort_t* __restrict__ hPl,
    ushort_t* __restrict__ sPh, ushort_t* __restrict__ sPl)
{
    const int idx = blockIdx.x * TB + threadIdx.x;   // 0..32767
    const int b = idx >> 9;
    const int j = idx & 511;

    float g[4];
    #pragma unroll
    for (int comp = 0; comp < 4; ++comp) {
        const int col = comp * 512 + j;
        float v = b_hh[col] + eW[((size_t)b * 20 + t) * 2048 + col];
        #pragma unroll
        for (int s = 0; s < 8; ++s)
            v += gates_part[(size_t)s * 64 * 2048 + (size_t)b * 2048 + col];
        #pragma unroll
        for (int s = 0; s < 4; ++s)
            v += hga_part[(size_t)s * 64 * 4608 + (size_t)b * 4608 + 2560 + col];
        g[comp] = v;
    }
    const float si = 1.f / (1.f + expf(-g[0]));
    const float sf = 1.f / (1.f + expf(-g[1]));
    const float gg = tanhf(g[2]);
    const float so = 1.f / (1.f + expf(-g[3]));
    const float cn = sf * c[idx] + si * gg;
    c[idx] = cn;
    const float hn = so * tanhf(cn);
    store_pack(hPh, hPl, 16, b, j, hn);
    store_pack(sPh, sPl, 16, b * 20 + t, j, hn);
}

// ------------------------- precompute helpers ------------------------------
__global__ __launch_bounds__(TB) void mean_feat(
    const float* __restrict__ features, float* __restrict__ mean_enc)
{
    const int b = blockIdx.y;
    const int e = blockIdx.x * TB + threadIdx.x;
    const float* f = features + (size_t)b * 196 * 2048 + e;
    float s = 0.f;
    #pragma unroll 4
    for (int p = 0; p < 196; ++p) s += f[(size_t)p * 2048];
    mean_enc[b * 2048 + e] = s * (1.f / 196.f);
}

__global__ __launch_bounds__(TB) void gather_emb_pack(
    const int* __restrict__ captions,
    const float* __restrict__ emb,
    ushort_t* __restrict__ Ph, ushort_t* __restrict__ Pl)
{
    const int bt = blockIdx.x;          // 0..1279
    const int b = bt / 20;
    const int t = bt % 20;
    const int tok = captions[b * 21 + t];
    for (int e = threadIdx.x; e < 512; e += TB)
        store_pack(Ph, Pl, 16, bt, e, emb[(size_t)tok * 512 + e]);
}

__global__ __launch_bounds__(TB) void reduce_hc(
    const float* __restrict__ h0p, const float* __restrict__ c0p,
    const float* __restrict__ bh0, const float* __restrict__ bc0,
    ushort_t* __restrict__ hPh, ushort_t* __restrict__ hPl,
    float* __restrict__ c)
{
    const int idx = blockIdx.x * TB + threadIdx.x;   // 0..65535
    const int half = idx >> 15;
    const int i = idx & 32767;
    const int j = i & 511;
    const float* P = half ? c0p : h0p;
    float v = half ? bc0[j] : bh0[j];
    #pragma unroll
    for (int s = 0; s < 8; ++s) v += P[(size_t)s * 64 * 512 + i];
    if (half) c[i] = v;
    else      store_pack(hPh, hPl, 16, i >> 9, j, v);
}

// ---------------------------------------------------------------------------
extern "C" void kernel_launch(void* const* d_in, const int* in_sizes, int n_in,
                              void* d_out, int out_size, void* d_ws, size_t ws_size,
                              hipStream_t stream)
{
    const float* features  = (const float*)d_in[0];
    const int*   captions  = (const int*)  d_in[1];
    const float* W_enc_att = (const float*)d_in[2];
    const float* b_enc_att = (const float*)d_in[3];
    const float* W_dec_att = (const float*)d_in[4];
    const float* b_dec_att = (const float*)d_in[5];
    const float* W_full    = (const float*)d_in[6];
    // d_in[7] = b_full : uniform shift -> softmax invariant, unused
    const float* emb       = (const float*)d_in[8];
    const float* W_ih      = (const float*)d_in[9];
    const float* W_hh      = (const float*)d_in[10];
    const float* b_ih      = (const float*)d_in[11];
    const float* b_hh      = (const float*)d_in[12];
    const float* W_init_h  = (const float*)d_in[13];
    const float* b_init_h  = (const float*)d_in[14];
    const float* W_init_c  = (const float*)d_in[15];
    const float* b_init_c  = (const float*)d_in[16];
    const float* W_fbeta   = (const float*)d_in[17];
    const float* b_fbeta   = (const float*)d_in[18];
    const float* W_fc      = (const float*)d_in[19];
    const float* b_fc      = (const float*)d_in[20];
    float* out = (float*)d_out;
    (void)ws_size;

    float* ws = (float*)d_ws;
    size_t off = 0;
    auto alloc  = [&](size_t n) { float* p = ws + off; off += n; return p; };
    auto ualloc = [&](size_t n) { ushort_t* p = (ushort_t*)(ws + off); off += (n + 1) / 2; return p; };

    float* eW     = alloc((size_t)64 * 20 * 2048);
    float* mean   = alloc(64 * 2048);
    float* hga    = alloc((size_t)4 * 64 * 4608);
    float* gatesp = alloc((size_t)8 * 64 * 2048);
    float* c      = alloc(64 * 512);
    float* scores = alloc(64 * 196);

    ushort_t* fbf    = ualloc((size_t)12544 * 2048);   // features bf16 (51.4 MB)
    ushort_t* att1bf = ualloc((size_t)12544 * 512);    // att1 bf16   (12.8 MB)
    ushort_t* WencH = ualloc((size_t)32 * 64 * 512);   // W_enc_att  (K2048, N512)
    ushort_t* WencL = ualloc((size_t)32 * 64 * 512);
    ushort_t* WtopH = ualloc((size_t)128 * 16 * 512);  // W_ih[:512] (K512, N2048)
    ushort_t* WtopL = ualloc((size_t)128 * 16 * 512);
    ushort_t* Wih2H = ualloc((size_t)128 * 64 * 512);  // W_ih[512:] (K2048, N2048)
    ushort_t* Wih2L = ualloc((size_t)128 * 64 * 512);
    ushort_t* WdfhH = ualloc((size_t)288 * 16 * 512);  // [Wd|Wf|Wh] (K512, N4608)
    ushort_t* WdfhL = ualloc((size_t)288 * 16 * 512);
    ushort_t* WfcH  = ualloc((size_t)632 * 16 * 512);  // W_fc       (K512, N10000->10112)
    ushort_t* WfcL  = ualloc((size_t)632 * 16 * 512);
    ushort_t* embsH = ualloc((size_t)80 * 16 * 512);   // embs  (M1280, K512)
    ushort_t* embsL = ualloc((size_t)80 * 16 * 512);
    ushort_t* hPh   = ualloc((size_t)4 * 16 * 512);    // h     (M64, K512)
    ushort_t* hPl   = ualloc((size_t)4 * 16 * 512);
    ushort_t* gPh   = ualloc((size_t)4 * 64 * 512);    // gated (M64, K2048)
    ushort_t* gPl   = ualloc((size_t)4 * 64 * 512);
    ushort_t* sPh   = ualloc((size_t)80 * 16 * 512);   // hseq  (M1280, K512)
    ushort_t* sPl   = ualloc((size_t)80 * 16 * 512);

    // one-time h0/c0 partials reuse step buffers (consumed before loop)
    float* h0p = hga;      // 8*64*512 <= 4*64*4608
    float* c0p = gatesp;   // 8*64*512 <= 8*64*2048

    // ---- pack all weights in ONE kernel ----
    PackJobs J;
    J.W[0]=W_enc_att;               J.Bh[0]=WencH; J.Bl[0]=WencL; J.Nsrc[0]=512;   J.ntCount[0]=32;  J.KC[0]=64; J.ntBase[0]=0;
    J.W[1]=W_ih;                    J.Bh[1]=WtopH; J.Bl[1]=WtopL; J.Nsrc[1]=2048;  J.ntCount[1]=128; J.KC[1]=16; J.ntBase[1]=0;
    J.W[2]=W_ih + (size_t)512*2048; J.Bh[2]=Wih2H; J.Bl[2]=Wih2L; J.Nsrc[2]=2048;  J.ntCount[2]=128; J.KC[2]=64; J.ntBase[2]=0;
    J.W[3]=W_dec_att;               J.Bh[3]=WdfhH; J.Bl[3]=WdfhL; J.Nsrc[3]=512;   J.ntCount[3]=32;  J.KC[3]=16; J.ntBase[3]=0;
    J.W[4]=W_fbeta;                 J.Bh[4]=WdfhH; J.Bl[4]=WdfhL; J.Nsrc[4]=2048;  J.ntCount[4]=128; J.KC[4]=16; J.ntBase[4]=32;
    J.W[5]=W_hh;                    J.Bh[5]=WdfhH; J.Bl[5]=WdfhL; J.Nsrc[5]=2048;  J.ntCount[5]=128; J.KC[5]=16; J.ntBase[5]=160;
    J.W[6]=W_fc;                    J.Bh[6]=WfcH;  J.Bl[6]=WfcL;  J.Nsrc[6]=10000; J.ntCount[6]=632; J.KC[6]=16; J.ntBase[6]=0;
    {
        int cum = 0;
        const int blks[7] = {512, 512, 2048, 128, 512, 512, 2528};
        for (int i = 0; i < 7; ++i) { J.cum[i] = cum; cum += blks[i]; }
        J.cum[7] = cum;
        pack_all<<<cum, TB, 0, stream>>>(J);
    }

    // ---- precompute (step-invariant) ----
    feat2bf<<<12544, TB, 0, stream>>>(features, fbf);
    gather_emb_pack<<<1280, TB, 0, stream>>>(captions, emb, embsH, embsL);
    mean_feat<<<dim3(8, 64), TB, 0, stream>>>(features, mean);
    gemm_hc<<<dim3(8, 16), TB, 0, stream>>>(mean, W_init_h, W_init_c, h0p, c0p);
    reduce_hc<<<256, TB, 0, stream>>>(h0p, c0p, b_init_h, b_init_c, hPh, hPl, c);
    // att1 = features @ W_enc_att + b -> bf16 : (12544 x 512), K=2048
    gemm_att1<<<dim3(4, 196), TB, 0, stream>>>(fbf, WencH, WencL, b_enc_att, att1bf);
    // eW = embs @ W_ih[:512] + b_ih : (1280 x 2048), K=512
    gemm_mfma<8, 8, 2, 2><<<dim3(16, 10, 1), TB, 0, stream>>>(
        embsH, embsL, WtopH, WtopL, 16, 16, b_ih, eW, 2048, 2048, 0);

    // ---- sequential decode ----
    for (int t = 0; t < 20; ++t) {
        // hga[ks] = h @ [Wd|Wf|Wh] partials : (64 x 4608), K=512 split 4
        gemm_mfma<4, 8, 2, 2><<<dim3(36, 1, 4), TB, 0, stream>>>(
            hPh, hPl, WdfhH, WdfhL, 16, 4, nullptr, hga, 4608, 4608, (size_t)64 * 4608);
        scores_k<<<dim3(64, 7), TB, 0, stream>>>(att1bf, hga, b_dec_att, W_full, scores);
        awe_gate<<<dim3(4, 64), 512, 0, stream>>>(scores, fbf, hga, b_fbeta, gPh, gPl);
        // gatesp[ks] = gated @ W_ih[512:] partials : (64 x 2048), K=2048 split 8
        gemm_mfma<4, 8, 2, 2><<<dim3(16, 1, 8), TB, 0, stream>>>(
            gPh, gPl, Wih2H, Wih2L, 64, 8, nullptr, gatesp, 2048, 2048, (size_t)64 * 2048);
        lstm_pw<<<128, TB, 0, stream>>>(gatesp, hga, eW, b_hh, t, c, hPh, hPl, sPh, sPl);
    }

    // preds = hseq @ W_fc + b_fc : (1280 x 10000), K=512
    gemm_mfma<8, 8, 2, 2><<<dim3(79, 10, 1), TB, 0, stream>>>(
        sPh, sPl, WfcH, WfcL, 16, 16, b_fc, out, 10000, 10000, 0);
}